// Round 3
// baseline (241.951 us; speedup 1.0000x reference)
//
#include <hip/hip_runtime.h>

// Inputs (setup_inputs order):
//   d_in[0] image_batch  [tf, 1024] f32
//   d_in[1] emo_batch    [tf, 1024] f32   (UNUSED by reference)
//   d_in[2] clip_batch   [tc, 1024] f32
//   d_in[3] num_frames_batch [B] i32
//   d_in[4] num_clips_batch  [B] i32
//   d_in[5] pad_idx (scalar i32)
// Output buffer is read by the harness as float32 throughout:
//   x [B, L, 2048] f32 flat, then src_length [B] stored as FLOAT values.

#define D_IMG 1024
#define D_TOT 2048

// One 256-thread block per output row (b, j). Each thread moves 2 float4:
// one from the image row, one from the clip row (or pad value).
// Prefix sums over nf/nc (B<=32 ints, L2-broadcast, wave-uniform scalar loop)
// are recomputed per block — cheaper than a serialized setup-kernel launch.
__global__ void __launch_bounds__(256)
gather_kernel(const float* __restrict__ image,
              const float* __restrict__ clip,
              const int* __restrict__ nf,
              const int* __restrict__ nc,
              const int* __restrict__ pad_idx_p,
              float* __restrict__ out,
              float* __restrict__ src_len,
              int L) {
    const int j = blockIdx.x;      // frame position within padded row
    const int b = blockIdx.y;      // batch index
    const int t = threadIdx.x;     // 0..255

    const int nf_b = nf[b];

    // src_length tail: one block per b writes it (as float — harness reads f32)
    if (j == 0 && t == 0) src_len[b] = (float)nf_b;

    float4* out4 = (float4*)(out + (size_t)(b * L + j) * D_TOT);

    if (j >= nf_b) {
        const float pv = (float)(*pad_idx_p);
        const float4 p4 = make_float4(pv, pv, pv, pv);
        out4[t]       = p4;
        out4[256 + t] = p4;
        return;
    }

    // wave-uniform exclusive prefix sums (b <= 31 iterations, scalar-unit work)
    int foff = 0, coff = 0;
    for (int i = 0; i < b; ++i) { foff += nf[i]; coff += nc[i]; }

    const int nc_b = nc[b];
    const int rf   = nf_b / nc_b;           // repeat factor (==4 here, computed generally)
    int cidx = j / rf;
    const int last = nc_b - 1;
    if (cidx > last) cidx = last;           // remainder tail clamps to last clip

    const float4* img4 = (const float4*)(image + (size_t)(foff + j) * D_IMG);
    const float4* clp4 = (const float4*)(clip  + (size_t)(coff + cidx) * D_IMG);

    out4[t]       = img4[t];                // elements [0,1024)
    out4[256 + t] = clp4[t];                // elements [1024,2048)
}

extern "C" void kernel_launch(void* const* d_in, const int* in_sizes, int n_in,
                              void* d_out, int out_size, void* d_ws, size_t ws_size,
                              hipStream_t stream) {
    const float* image = (const float*)d_in[0];
    // d_in[1] (emo_batch) is unused by the reference.
    const float* clip  = (const float*)d_in[2];
    const int*   nf    = (const int*)d_in[3];
    const int*   nc    = (const int*)d_in[4];
    const int*   pad   = (const int*)d_in[5];

    const int B = in_sizes[3];
    const int L = (out_size - B) / (B * D_TOT);

    float* out = (float*)d_out;
    float* src_len = (float*)d_out + (size_t)B * L * D_TOT;  // tail: src_length [B]

    dim3 grid(L, B);
    gather_kernel<<<grid, 256, 0, stream>>>(image, clip, nf, nc, pad, out, src_len, L);
}

// Round 5
// 238.238 us; speedup vs baseline: 1.0156x; 1.0156x over previous
//
#include <hip/hip_runtime.h>

// Inputs (setup_inputs order):
//   d_in[0] image_batch  [tf, 1024] f32
//   d_in[1] emo_batch    [tf, 1024] f32   (UNUSED by reference)
//   d_in[2] clip_batch   [tc, 1024] f32
//   d_in[3] num_frames_batch [B] i32
//   d_in[4] num_clips_batch  [B] i32
//   d_in[5] pad_idx (scalar i32)
// Output buffer is read by the harness as float32 throughout:
//   x [B, L, 2048] f32 flat, then src_length [B] stored as FLOAT values.
//
// R3 profiling: harness re-poison fills (~2 x 94us at 6.6 TB/s) dominate
// dur_us (~188us floor); gather itself ~54us. R4: NT builtins need clang
// ext_vector types, not HIP_vector_type float4.

#define D_IMG 1024
#define D_TOT 2048

typedef float f32x4 __attribute__((ext_vector_type(4)));

// One 256-thread block per output row (b, j). Each thread moves 2 f32x4.
__global__ void __launch_bounds__(256)
gather_kernel(const float* __restrict__ image,
              const float* __restrict__ clip,
              const int* __restrict__ nf,
              const int* __restrict__ nc,
              const int* __restrict__ pad_idx_p,
              float* __restrict__ out,
              float* __restrict__ src_len,
              int L, int B) {
    const int j = blockIdx.x;      // frame position within padded row
    const int b = blockIdx.y;      // batch index
    const int t = threadIdx.x;     // 0..255
    const int lane = t & 63;

    // Wave-parallel exclusive prefix sums: lane i holds nf[i]/nc[i] (i < B),
    // mask lanes >= b, butterfly-reduce. Replaces a serial loop of up to 31
    // dependent scalar-load pairs. All 4 waves compute redundantly.
    int nfv = 0, ncv = 0;
    if (lane < B) { nfv = nf[lane]; ncv = nc[lane]; }
    const int nf_b = __shfl(nfv, b);
    const int nc_b = __shfl(ncv, b);
    int fo = (lane < b) ? nfv : 0;
    int co = (lane < b) ? ncv : 0;
    #pragma unroll
    for (int off = 32; off > 0; off >>= 1) {
        fo += __shfl_xor(fo, off);
        co += __shfl_xor(co, off);
    }
    // fo = foff[b], co = coff[b], uniform across the wave now.

    if (j == 0 && t == 0) src_len[b] = (float)nf_b;  // harness reads f32

    f32x4* out4 = (f32x4*)(out + (size_t)(b * L + j) * D_TOT);

    if (j >= nf_b) {
        const float pv = (float)(*pad_idx_p);
        const f32x4 p4 = {pv, pv, pv, pv};
        __builtin_nontemporal_store(p4, &out4[t]);
        __builtin_nontemporal_store(p4, &out4[256 + t]);
        return;
    }

    const int rf = nf_b / nc_b;             // repeat factor (==4 here, general)
    int cidx = j / rf;
    const int last = nc_b - 1;
    if (cidx > last) cidx = last;           // remainder tail clamps to last clip

    const f32x4* img4 = (const f32x4*)(image + (size_t)(fo + j) * D_IMG);
    const f32x4* clp4 = (const f32x4*)(clip  + (size_t)(co + cidx) * D_IMG);

    // image: read-once stream -> nontemporal load; clip: 4x reuse -> cached.
    f32x4 iv = __builtin_nontemporal_load(&img4[t]);
    f32x4 cv = clp4[t];
    __builtin_nontemporal_store(iv, &out4[t]);          // elements [0,1024)
    __builtin_nontemporal_store(cv, &out4[256 + t]);    // elements [1024,2048)
}

extern "C" void kernel_launch(void* const* d_in, const int* in_sizes, int n_in,
                              void* d_out, int out_size, void* d_ws, size_t ws_size,
                              hipStream_t stream) {
    const float* image = (const float*)d_in[0];
    // d_in[1] (emo_batch) is unused by the reference.
    const float* clip  = (const float*)d_in[2];
    const int*   nf    = (const int*)d_in[3];
    const int*   nc    = (const int*)d_in[4];
    const int*   pad   = (const int*)d_in[5];

    const int B = in_sizes[3];
    const int L = (out_size - B) / (B * D_TOT);

    float* out = (float*)d_out;
    float* src_len = (float*)d_out + (size_t)B * L * D_TOT;  // tail: src_length [B]

    dim3 grid(L, B);
    gather_kernel<<<grid, 256, 0, stream>>>(image, clip, nf, nc, pad, out, src_len, L, B);
}